// Round 5
// baseline (183.360 us; speedup 1.0000x reference)
//
#include <hip/hip_runtime.h>
#include <hip/hip_fp16.h>
#include <cmath>

#define DF 128           // feature dim
#define TR 128           // gemm rows per block tile
#define KC 32            // gemm K chunk staged in LDS
#define PITCH 36         // LDS row pitch (32 data + 4 pad floats, 144 B = 16B aligned)

// ---------------------------------------------------------------------------
// Kernel 1: support[n][o] = (fp16) sum_d X[n][d] * W[o][d] + b[o]
// 256 threads, 128x128 tile, 8x8/thread with STRIDED ownership:
//   rows r = ty + 16*i  -> X-frag b128 read bank quad = (4*ty + dt) mod 32;
//       wave's 4 ty values give 4 distinct quads (16-lane broadcast each)
//       -> conflict-free.  (note 16*i*36 = 576*i == 0 mod 32, irrelevant
//       since each i is a separate instruction)
//   cols c = tx + 16*j  -> W-frag read bank quad = (4*tx + dt) mod 32;
//       tx and tx+8 share a quad with distinct addrs -> 2-way (free, m136).
// Staging: float4 ds_write_b128, bank quad = 4*((r + (t&7)) mod 8) ->
// uniform 8 lanes/quad = minimum cost. All addressing compile-time affine.
// ---------------------------------------------------------------------------
__global__ __launch_bounds__(256)
void gemm_bias_kernel(const float* __restrict__ X, const float* __restrict__ W,
                      const float* __restrict__ bias, __half* __restrict__ S,
                      int N)
{
    __shared__ float Xs[TR * PITCH];   // 18 KB
    __shared__ float Ws[DF * PITCH];   // 18 KB

    const int t  = threadIdx.x;
    const int tx = t & 15;             // cols: tx + 16*j
    const int ty = t >> 4;             // rows: ty + 16*i
    const int r0 = blockIdx.x * TR;

    float acc[8][8];
    #pragma unroll
    for (int i = 0; i < 8; ++i)
        #pragma unroll
        for (int j = 0; j < 8; ++j) acc[i][j] = 0.f;

    for (int kc = 0; kc < DF; kc += KC) {
        // ---- stage X chunk: 128 rows x 32 k, one float4 per thread x4 ----
        #pragma unroll
        for (int l = 0; l < 4; ++l) {
            int flat = l * 256 + t;            // 0..1023
            int r    = flat >> 3;              // 0..127
            int dl   = (flat & 7) * 4;         // 0,4,...,28
            float4 v = make_float4(0.f, 0.f, 0.f, 0.f);
            if (r0 + r < N) v = *(const float4*)(X + (size_t)(r0 + r) * DF + kc + dl);
            *(float4*)(Xs + r * PITCH + dl) = v;
        }
        // ---- stage W chunk: out-cols 0..127 ----
        #pragma unroll
        for (int l = 0; l < 4; ++l) {
            int flat = l * 256 + t;
            int c    = flat >> 3;
            int dl   = (flat & 7) * 4;
            float4 v = *(const float4*)(W + (size_t)c * DF + kc + dl);
            *(float4*)(Ws + c * PITCH + dl) = v;
        }
        __syncthreads();

        // ---- accumulate over the 32-wide chunk, 4 k at a time ----
        #pragma unroll
        for (int dt = 0; dt < KC; dt += 4) {
            float4 xv[8];
            #pragma unroll
            for (int i = 0; i < 8; ++i)
                xv[i] = *(const float4*)(Xs + (ty + 16 * i) * PITCH + dt);
            #pragma unroll
            for (int j = 0; j < 8; ++j) {
                float4 wv = *(const float4*)(Ws + (tx + 16 * j) * PITCH + dt);
                #pragma unroll
                for (int i = 0; i < 8; ++i) {
                    acc[i][j] += xv[i].x * wv.x + xv[i].y * wv.y
                               + xv[i].z * wv.z + xv[i].w * wv.w;
                }
            }
        }
        __syncthreads();
    }

    // ---- epilogue: bias + fp16 store (scalar halves, 32 B coalesced runs) ----
    float bj[8];
    #pragma unroll
    for (int j = 0; j < 8; ++j) bj[j] = bias[tx + 16 * j];
    #pragma unroll
    for (int i = 0; i < 8; ++i) {
        int gr = r0 + ty + 16 * i;
        if (gr < N) {
            __half* row = S + (size_t)gr * DF;
            #pragma unroll
            for (int j = 0; j < 8; ++j)
                row[tx + 16 * j] = __float2half(acc[i][j] + bj[j]);
        }
    }
}

// ---------------------------------------------------------------------------
// Kernel 2: CSR row pointers + packed edge metadata {byte_offset, val_bits}.
// fp16 S rows are 256 B -> offset = col << 8.
// ---------------------------------------------------------------------------
__global__ __launch_bounds__(256)
void build_meta_kernel(const int* __restrict__ arow, const int* __restrict__ acol,
                       const float* __restrict__ aval,
                       int* __restrict__ rowptr, int2* __restrict__ pk,
                       int N, int E)
{
    int e = blockIdx.x * 256 + threadIdx.x;
    if (e >= E) return;
    pk[e] = make_int2(acol[e] << 8, __float_as_int(aval[e]));
    int r = arow[e];
    int rprev = (e == 0) ? -1 : arow[e - 1];
    for (int n = rprev + 1; n <= r; ++n) rowptr[n] = e;
    if (e == E - 1) {
        for (int n = r + 1; n <= N; ++n) rowptr[n] = E;
    }
}

// ---------------------------------------------------------------------------
// Kernel 3: out[n][:] = tanh( sum_e val[e]*S_fp16[col[e]][:] ) per CSR row.
// One 64-lane wave per node (node id forced uniform -> rowptr/pk via scalar
// pipe). Each edge gather = 64 lanes x __half2 (4 B) = one 256 B wave read
// off an SGPR base. 8 edges in flight, fp32 accumulation, 2 chains.
// ---------------------------------------------------------------------------
__global__ __launch_bounds__(256)
void agg_tanh_kernel(const __half* __restrict__ S, const int* __restrict__ rowptr,
                     const int2* __restrict__ pk, float* __restrict__ out, int Nn)
{
    const int n = __builtin_amdgcn_readfirstlane(blockIdx.x * 4 + (threadIdx.x >> 6));
    if (n >= Nn) return;
    const int lane = threadIdx.x & 63;
    const int l4   = lane * 4;

    const int start = rowptr[n];
    const int end   = rowptr[n + 1];
    const char* Sb  = (const char*)S;

    float2 a0; a0.x = 0.f; a0.y = 0.f;
    float2 a1; a1.x = 0.f; a1.y = 0.f;

    int e = start;
    for (; e + 8 <= end; e += 8) {
        __half2 h[8]; float v[8];
        #pragma unroll
        for (int u = 0; u < 8; ++u) {
            int2 p = pk[e + u];
            h[u] = *(const __half2*)(Sb + (size_t)(unsigned)p.x + l4);
            v[u] = __int_as_float(p.y);
        }
        #pragma unroll
        for (int u = 0; u < 8; ++u) {
            float2 s = __half22float2(h[u]);
            if (u & 1) { a1.x += v[u] * s.x; a1.y += v[u] * s.y; }
            else       { a0.x += v[u] * s.x; a0.y += v[u] * s.y; }
        }
    }
    if (e + 4 <= end) {
        __half2 h[4]; float v[4];
        #pragma unroll
        for (int u = 0; u < 4; ++u) {
            int2 p = pk[e + u];
            h[u] = *(const __half2*)(Sb + (size_t)(unsigned)p.x + l4);
            v[u] = __int_as_float(p.y);
        }
        #pragma unroll
        for (int u = 0; u < 4; ++u) {
            float2 s = __half22float2(h[u]);
            if (u & 1) { a1.x += v[u] * s.x; a1.y += v[u] * s.y; }
            else       { a0.x += v[u] * s.x; a0.y += v[u] * s.y; }
        }
        e += 4;
    }
    for (; e < end; ++e) {
        int2 p = pk[e];
        float2 s = __half22float2(*(const __half2*)(Sb + (size_t)(unsigned)p.x + l4));
        float v = __int_as_float(p.y);
        a0.x += v * s.x; a0.y += v * s.y;
    }

    float2 o;
    o.x = tanhf(a0.x + a1.x);
    o.y = tanhf(a0.y + a1.y);
    *(float2*)(out + (size_t)n * DF + lane * 2) = o;
}

// ---------------------------------------------------------------------------
extern "C" void kernel_launch(void* const* d_in, const int* in_sizes, int n_in,
                              void* d_out, int out_size, void* d_ws, size_t ws_size,
                              hipStream_t stream)
{
    const float* X    = (const float*)d_in[0];   // [N, 128]
    const float* W    = (const float*)d_in[1];   // [128, 128]
    const float* bias = (const float*)d_in[2];   // [128]
    const int*   arow = (const int*)  d_in[3];   // [E] sorted
    const int*   acol = (const int*)  d_in[4];   // [E]
    const float* aval = (const float*)d_in[5];   // [E]
    float* out = (float*)d_out;

    const int N = in_sizes[0] / DF;
    const int E = in_sizes[3];

    // ws layout: S [N*128 fp16 = 12.8 MB] | rowptr [N+2 ints] | pk [E int2]
    __half* S      = (__half*)d_ws;
    int*    rowptr = (int*)((char*)d_ws + (size_t)N * DF * sizeof(__half));
    int2*   pk     = (int2*)(rowptr + (N + 2));

    build_meta_kernel<<<(E + 255) / 256, 256, 0, stream>>>(arow, acol, aval,
                                                           rowptr, pk, N, E);

    gemm_bias_kernel<<<(N + TR - 1) / TR, 256, 0, stream>>>(X, W, bias, S, N);

    agg_tanh_kernel<<<(N + 3) / 4, 256, 0, stream>>>(S, rowptr, pk, out, N);
}

// Round 6
// 131.803 us; speedup vs baseline: 1.3912x; 1.3912x over previous
//
#include <hip/hip_runtime.h>
#include <hip/hip_fp16.h>
#include <cmath>

#define DF 128           // feature dim

typedef _Float16 f16x8 __attribute__((ext_vector_type(8)));
typedef float    f32x4 __attribute__((ext_vector_type(4)));

// ---------------------------------------------------------------------------
// Kernel 1: support[n][o] = (fp16) sum_d X[n][d] * W[o][d] + b[o]  via MFMA.
// One 64-lane wave per 16-row m-strip; 8 n-tiles of 16; K=128 in 4 chunks.
// No LDS, no barriers. Fragment layouts (verified, m89/m120):
//   A[m=lane&15][k=(lane>>4)*8+j]  <- X rows direct (fp32->fp16 cvt inline);
//      the 4 lane-quads of a wave read one 128 B line per row -> X read 1x.
//   B[n=lane&15][k=(lane>>4)*8+j]  <- Wh (pre-converted fp16 W, 32 KB: L1-resident).
//   C/D: col=lane&15, row=(lane>>4)*4+reg.
// ---------------------------------------------------------------------------
__global__ __launch_bounds__(256)
void gemm_mfma_kernel(const float* __restrict__ X, const _Float16* __restrict__ Wh,
                      const float* __restrict__ bias, __half* __restrict__ S,
                      int N)
{
    const int wave = threadIdx.x >> 6;
    const int lane = threadIdx.x & 63;
    const int l15  = lane & 15;
    const int q    = lane >> 4;                    // 0..3
    const int m0   = (blockIdx.x * 4 + wave) * 16;
    if (m0 >= N) return;

    f32x4 acc[8];
    #pragma unroll
    for (int nt = 0; nt < 8; ++nt) acc[nt] = (f32x4){0.f, 0.f, 0.f, 0.f};

    const int arow = min(m0 + l15, N - 1);         // clamp (dup read) for tail
    #pragma unroll
    for (int kc = 0; kc < DF; kc += 32) {
        const float* xp = X + (size_t)arow * DF + kc + q * 8;
        float4 xa = *(const float4*)xp;
        float4 xb = *(const float4*)(xp + 4);
        f16x8 A;
        A[0] = (_Float16)xa.x; A[1] = (_Float16)xa.y;
        A[2] = (_Float16)xa.z; A[3] = (_Float16)xa.w;
        A[4] = (_Float16)xb.x; A[5] = (_Float16)xb.y;
        A[6] = (_Float16)xb.z; A[7] = (_Float16)xb.w;
        #pragma unroll
        for (int nt = 0; nt < 8; ++nt) {
            f16x8 B = *(const f16x8*)(Wh + (size_t)(nt * 16 + l15) * DF + kc + q * 8);
            acc[nt] = __builtin_amdgcn_mfma_f32_16x16x32_f16(A, B, acc[nt], 0, 0, 0);
        }
    }

    // ---- epilogue: bias + fp16 stores (per instr: 4 rows x 32 B runs) ----
    #pragma unroll
    for (int nt = 0; nt < 8; ++nt) {
        float bj = bias[nt * 16 + l15];
        #pragma unroll
        for (int r = 0; r < 4; ++r) {
            int gr = m0 + q * 4 + r;
            if (gr < N)
                S[(size_t)gr * DF + nt * 16 + l15] = __float2half(acc[nt][r] + bj);
        }
    }
}

// ---------------------------------------------------------------------------
// Kernel 2: CSR row pointers + packed edge metadata {byte_offset, val_bits}
// + one-time W fp32->fp16 conversion (first 16384 threads).
// fp16 S rows are 256 B -> offset = col << 8.
// ---------------------------------------------------------------------------
__global__ __launch_bounds__(256)
void build_meta_kernel(const int* __restrict__ arow, const int* __restrict__ acol,
                       const float* __restrict__ aval, const float* __restrict__ W,
                       int* __restrict__ rowptr, int2* __restrict__ pk,
                       _Float16* __restrict__ Wh, int N, int E)
{
    int e = blockIdx.x * 256 + threadIdx.x;
    if (e >= E) return;
    if (e < DF * DF) Wh[e] = (_Float16)W[e];
    pk[e] = make_int2(acol[e] << 8, __float_as_int(aval[e]));
    int r = arow[e];
    int rprev = (e == 0) ? -1 : arow[e - 1];
    for (int n = rprev + 1; n <= r; ++n) rowptr[n] = e;
    if (e == E - 1) {
        for (int n = r + 1; n <= N; ++n) rowptr[n] = E;
    }
}

// ---------------------------------------------------------------------------
// Kernel 3: out[n][:] = tanh( sum_e val[e]*S_fp16[col[e]][:] ) per CSR row.
// One 64-lane wave per node (node id forced uniform -> rowptr/pk via scalar
// pipe). Each edge gather = 64 lanes x __half2 (4 B) = one 256 B wave read
// off an SGPR base. 8 edges in flight, fp32 accumulation, 2 chains.
// ---------------------------------------------------------------------------
__global__ __launch_bounds__(256)
void agg_tanh_kernel(const __half* __restrict__ S, const int* __restrict__ rowptr,
                     const int2* __restrict__ pk, float* __restrict__ out, int Nn)
{
    const int n = __builtin_amdgcn_readfirstlane(blockIdx.x * 4 + (threadIdx.x >> 6));
    if (n >= Nn) return;
    const int lane = threadIdx.x & 63;
    const int l4   = lane * 4;

    const int start = rowptr[n];
    const int end   = rowptr[n + 1];
    const char* Sb  = (const char*)S;

    float2 a0; a0.x = 0.f; a0.y = 0.f;
    float2 a1; a1.x = 0.f; a1.y = 0.f;

    int e = start;
    for (; e + 8 <= end; e += 8) {
        __half2 h[8]; float v[8];
        #pragma unroll
        for (int u = 0; u < 8; ++u) {
            int2 p = pk[e + u];
            h[u] = *(const __half2*)(Sb + (size_t)(unsigned)p.x + l4);
            v[u] = __int_as_float(p.y);
        }
        #pragma unroll
        for (int u = 0; u < 8; ++u) {
            float2 s = __half22float2(h[u]);
            if (u & 1) { a1.x += v[u] * s.x; a1.y += v[u] * s.y; }
            else       { a0.x += v[u] * s.x; a0.y += v[u] * s.y; }
        }
    }
    if (e + 4 <= end) {
        __half2 h[4]; float v[4];
        #pragma unroll
        for (int u = 0; u < 4; ++u) {
            int2 p = pk[e + u];
            h[u] = *(const __half2*)(Sb + (size_t)(unsigned)p.x + l4);
            v[u] = __int_as_float(p.y);
        }
        #pragma unroll
        for (int u = 0; u < 4; ++u) {
            float2 s = __half22float2(h[u]);
            if (u & 1) { a1.x += v[u] * s.x; a1.y += v[u] * s.y; }
            else       { a0.x += v[u] * s.x; a0.y += v[u] * s.y; }
        }
        e += 4;
    }
    for (; e < end; ++e) {
        int2 p = pk[e];
        float2 s = __half22float2(*(const __half2*)(Sb + (size_t)(unsigned)p.x + l4));
        float v = __int_as_float(p.y);
        a0.x += v * s.x; a0.y += v * s.y;
    }

    float2 o;
    o.x = tanhf(a0.x + a1.x);
    o.y = tanhf(a0.y + a1.y);
    *(float2*)(out + (size_t)n * DF + lane * 2) = o;
}

// ---------------------------------------------------------------------------
extern "C" void kernel_launch(void* const* d_in, const int* in_sizes, int n_in,
                              void* d_out, int out_size, void* d_ws, size_t ws_size,
                              hipStream_t stream)
{
    const float* X    = (const float*)d_in[0];   // [N, 128]
    const float* W    = (const float*)d_in[1];   // [128, 128]
    const float* bias = (const float*)d_in[2];   // [128]
    const int*   arow = (const int*)  d_in[3];   // [E] sorted
    const int*   acol = (const int*)  d_in[4];   // [E]
    const float* aval = (const float*)d_in[5];   // [E]
    float* out = (float*)d_out;

    const int N = in_sizes[0] / DF;
    const int E = in_sizes[3];

    // ws layout: S [N*128 fp16] | Wh [128*128 fp16, 16B-aligned] | rowptr | pk
    __half*   S      = (__half*)d_ws;
    _Float16* Wh     = (_Float16*)((char*)d_ws + (size_t)N * DF * sizeof(__half));
    int*      rowptr = (int*)((char*)Wh + (size_t)DF * DF * sizeof(_Float16));
    int2*     pk     = (int2*)(rowptr + (N + 2));

    build_meta_kernel<<<(E + 255) / 256, 256, 0, stream>>>(arow, acol, aval, W,
                                                           rowptr, pk, Wh, N, E);

    const int mstrips = (N + 15) / 16;
    gemm_mfma_kernel<<<(mstrips + 3) / 4, 256, 0, stream>>>(X, Wh, bias, S, N);

    agg_tanh_kernel<<<(N + 3) / 4, 256, 0, stream>>>(S, rowptr, pk, out, N);
}

// Round 7
// 129.049 us; speedup vs baseline: 1.4209x; 1.0213x over previous
//
#include <hip/hip_runtime.h>
#include <hip/hip_fp16.h>
#include <cmath>

#define DF 128            // feature dim
#define WPITCHH 136       // LDS W row pitch in halves (128 + 8 pad -> 272 B, odd dword stride)

typedef _Float16 f16x8 __attribute__((ext_vector_type(8)));
typedef float    f32x4 __attribute__((ext_vector_type(4)));

// ---------------------------------------------------------------------------
// Kernel 1: support[n][o] = (fp16) sum_d X[n][d] * W[o][d] + b[o]  via MFMA.
// One 64-lane wave per 16-row m-strip, 4 waves/block (64 rows/block).
// Whole fp16 W (32 KB) staged ONCE per block into LDS with pitch 136 halves
// (68 dwords, odd): B-frag b128 reads hit quad (17*l15 + q) mod 32 -> max
// 2-way alias (free, m136); staging writes likewise <=2-way.
// A-frag straight from X (fp32->fp16 inline); lanes of a quad cover one
// 128 B line per row -> X fetched exactly once.
// Layouts (verified r6): A/B [idx=lane&15][k=(lane>>4)*8+j]; C/D col=lane&15,
// row=(lane>>4)*4+reg.
// ---------------------------------------------------------------------------
__global__ __launch_bounds__(256)
void gemm_mfma_kernel(const float* __restrict__ X, const _Float16* __restrict__ Wh,
                      const float* __restrict__ bias, __half* __restrict__ S,
                      int N)
{
    __shared__ _Float16 Wl[DF * WPITCHH];          // 34 KB

    const int t    = threadIdx.x;
    const int lane = t & 63;
    const int l15  = lane & 15;
    const int q    = lane >> 4;                    // 0..3
    const int m0   = (blockIdx.x * 4 + (t >> 6)) * 16;

    // ---- stage all of Wh into LDS (all waves participate; barrier before
    //      any early-out) ----
    #pragma unroll
    for (int l = 0; l < 8; ++l) {
        int flat = l * 256 + t;                    // 0..2047
        int r    = flat >> 4;                      // 0..127
        int c8   = (flat & 15) * 8;                // 0..120
        f16x8 v = *(const f16x8*)(Wh + (size_t)r * DF + c8);
        *(f16x8*)(Wl + r * WPITCHH + c8) = v;
    }
    __syncthreads();
    if (m0 >= N) return;

    f32x4 acc[8];
    #pragma unroll
    for (int nt = 0; nt < 8; ++nt) acc[nt] = (f32x4){0.f, 0.f, 0.f, 0.f};

    const int arow = min(m0 + l15, N - 1);         // clamp (dup read) for tail
    #pragma unroll
    for (int kc = 0; kc < DF; kc += 32) {
        const float* xp = X + (size_t)arow * DF + kc + q * 8;
        float4 xa = *(const float4*)xp;
        float4 xb = *(const float4*)(xp + 4);
        f16x8 A;
        A[0] = (_Float16)xa.x; A[1] = (_Float16)xa.y;
        A[2] = (_Float16)xa.z; A[3] = (_Float16)xa.w;
        A[4] = (_Float16)xb.x; A[5] = (_Float16)xb.y;
        A[6] = (_Float16)xb.z; A[7] = (_Float16)xb.w;
        #pragma unroll
        for (int nt = 0; nt < 8; ++nt) {
            f16x8 B = *(const f16x8*)(Wl + (nt * 16 + l15) * WPITCHH + kc + q * 8);
            acc[nt] = __builtin_amdgcn_mfma_f32_16x16x32_f16(A, B, acc[nt], 0, 0, 0);
        }
    }

    // ---- epilogue: bias + fp16 stores ----
    #pragma unroll
    for (int nt = 0; nt < 8; ++nt) {
        float bj = bias[nt * 16 + l15];
        #pragma unroll
        for (int r = 0; r < 4; ++r) {
            int gr = m0 + q * 4 + r;
            if (gr < N)
                S[(size_t)gr * DF + nt * 16 + l15] = __float2half(acc[nt][r] + bj);
        }
    }
}

// ---------------------------------------------------------------------------
// Kernel 2: CSR row pointers + packed edge metadata {byte_offset, val_bits}
// + one-time W fp32->fp16 conversion. fp16 S rows are 256 B -> col << 8.
// ---------------------------------------------------------------------------
__global__ __launch_bounds__(256)
void build_meta_kernel(const int* __restrict__ arow, const int* __restrict__ acol,
                       const float* __restrict__ aval, const float* __restrict__ W,
                       int* __restrict__ rowptr, int2* __restrict__ pk,
                       _Float16* __restrict__ Wh, int N, int E)
{
    int e = blockIdx.x * 256 + threadIdx.x;
    if (e >= E) return;
    if (e < DF * DF) Wh[e] = (_Float16)W[e];
    pk[e] = make_int2(acol[e] << 8, __float_as_int(aval[e]));
    int r = arow[e];
    int rprev = (e == 0) ? -1 : arow[e - 1];
    for (int n = rprev + 1; n <= r; ++n) rowptr[n] = e;
    if (e == E - 1) {
        for (int n = r + 1; n <= N; ++n) rowptr[n] = E;
    }
}

// ---------------------------------------------------------------------------
// Kernel 3: out[n][:] = tanh( sum_e val[e]*S_fp16[col[e]][:] ) per CSR row.
// One wave per node, but 4 EDGES PROCESSED IN PARALLEL: 16-lane group g
// (g=lane>>4) handles edge base+g / base+4+g; lane grabs 16 B (8 features,
// dwordx4). Per 8 edges: 2 pk loads + 2 gathers (vs 16 loads before), 4x
// shorter dependency chain. Cross-group butterfly (shfl_xor 16,32) at the
// end, fused tanh, float4 stores from group 0. Padded slots read row 0 with
// val=0 (harmless).
// ---------------------------------------------------------------------------
__global__ __launch_bounds__(256)
void agg_tanh_kernel(const __half* __restrict__ S, const int* __restrict__ rowptr,
                     const int2* __restrict__ pk, float* __restrict__ out, int Nn)
{
    const int n = __builtin_amdgcn_readfirstlane(blockIdx.x * 4 + (threadIdx.x >> 6));
    if (n >= Nn) return;
    const int lane = threadIdx.x & 63;
    const int g    = lane >> 4;                    // edge slot 0..3
    const int fb   = (lane & 15) * 16;             // byte offset of 8-feature chunk

    const int start = rowptr[n];
    const int end   = rowptr[n + 1];
    const char* Sb  = (const char*)S;

    float acc[8];
    #pragma unroll
    for (int i = 0; i < 8; ++i) acc[i] = 0.f;

    for (int base = start; base < end; base += 8) {
        const int e0 = base + g;
        const int e1 = base + 4 + g;
        int2 p0 = (e0 < end) ? pk[e0] : make_int2(0, 0);
        int2 p1 = (e1 < end) ? pk[e1] : make_int2(0, 0);
        f16x8 h0 = *(const f16x8*)(Sb + (size_t)(unsigned)p0.x + fb);
        f16x8 h1 = *(const f16x8*)(Sb + (size_t)(unsigned)p1.x + fb);
        const float v0 = __int_as_float(p0.y);
        const float v1 = __int_as_float(p1.y);
        #pragma unroll
        for (int i = 0; i < 8; ++i)
            acc[i] += (float)h0[i] * v0 + (float)h1[i] * v1;
    }

    // reduce the 4 edge-groups (each holds a partial sum of the same 8 features)
    #pragma unroll
    for (int i = 0; i < 8; ++i) {
        acc[i] += __shfl_xor(acc[i], 16);
        acc[i] += __shfl_xor(acc[i], 32);
    }

    if (g == 0) {
        float4 o0, o1;
        o0.x = tanhf(acc[0]); o0.y = tanhf(acc[1]);
        o0.z = tanhf(acc[2]); o0.w = tanhf(acc[3]);
        o1.x = tanhf(acc[4]); o1.y = tanhf(acc[5]);
        o1.z = tanhf(acc[6]); o1.w = tanhf(acc[7]);
        float* op = out + (size_t)n * DF + (lane & 15) * 8;
        *(float4*)op       = o0;
        *(float4*)(op + 4) = o1;
    }
}

// ---------------------------------------------------------------------------
extern "C" void kernel_launch(void* const* d_in, const int* in_sizes, int n_in,
                              void* d_out, int out_size, void* d_ws, size_t ws_size,
                              hipStream_t stream)
{
    const float* X    = (const float*)d_in[0];   // [N, 128]
    const float* W    = (const float*)d_in[1];   // [128, 128]
    const float* bias = (const float*)d_in[2];   // [128]
    const int*   arow = (const int*)  d_in[3];   // [E] sorted
    const int*   acol = (const int*)  d_in[4];   // [E]
    const float* aval = (const float*)d_in[5];   // [E]
    float* out = (float*)d_out;

    const int N = in_sizes[0] / DF;
    const int E = in_sizes[3];

    // ws layout: S [N*128 fp16] | Wh [128*128 fp16] | rowptr [N+2] | pk [E int2]
    __half*   S      = (__half*)d_ws;
    _Float16* Wh     = (_Float16*)((char*)d_ws + (size_t)N * DF * sizeof(__half));
    int*      rowptr = (int*)((char*)Wh + (size_t)DF * DF * sizeof(_Float16));
    int2*     pk     = (int2*)(rowptr + (N + 2));

    build_meta_kernel<<<(E + 255) / 256, 256, 0, stream>>>(arow, acol, aval, W,
                                                           rowptr, pk, Wh, N, E);

    gemm_mfma_kernel<<<(N + 63) / 64, 256, 0, stream>>>(X, Wh, bias, S, N);

    agg_tanh_kernel<<<(N + 3) / 4, 256, 0, stream>>>(S, rowptr, pk, out, N);
}

// Round 8
// 124.143 us; speedup vs baseline: 1.4770x; 1.0395x over previous
//
#include <hip/hip_runtime.h>
#include <hip/hip_fp16.h>
#include <cmath>

#define DF 128            // feature dim
#define WPITCHH 136       // LDS W row pitch in halves (128 + 8 pad, 272 B, odd dword stride)

typedef _Float16 f16x8 __attribute__((ext_vector_type(8)));
typedef _Float16 f16x4 __attribute__((ext_vector_type(4)));
typedef float    f32x4 __attribute__((ext_vector_type(4)));

// ---------------------------------------------------------------------------
// Kernel 1: support[n][o] = (fp16) sum_d X[n][d] * W[o][d] + b[o]  via MFMA.
// One 64-lane wave per 16-row m-strip, 4 waves/block. fp16 W staged once per
// block in LDS (pitch 136 halves -> <=2-way bank alias, free).
// OPERAND-SWAP trick: mfma(Wfrag, Xfrag) -> D[o][node]; C/D layout
// (col=lane&15, row=(lane>>4)*4+reg) then gives lane l15 the node row
// m0+l15 with 4 CONSECUTIVE o-columns per nt: epilogue is 8 f16x4 stores
// per lane (was 32 scalar 2-byte stores).
// A/B frags both use [idx=lane&15][k=(lane>>4)*8+j] so the swap is free.
// ---------------------------------------------------------------------------
__global__ __launch_bounds__(256)
void gemm_mfma_kernel(const float* __restrict__ X, const _Float16* __restrict__ Wh,
                      const float* __restrict__ bias, __half* __restrict__ S,
                      int N)
{
    __shared__ _Float16 Wl[DF * WPITCHH];          // 34 KB

    const int t    = threadIdx.x;
    const int lane = t & 63;
    const int l15  = lane & 15;
    const int q    = lane >> 4;                    // 0..3
    const int m0   = (blockIdx.x * 4 + (t >> 6)) * 16;

    // ---- stage all of Wh into LDS (all waves; barrier before early-out) ----
    #pragma unroll
    for (int l = 0; l < 8; ++l) {
        int flat = l * 256 + t;                    // 0..2047
        int r    = flat >> 4;                      // 0..127
        int c8   = (flat & 15) * 8;                // 0..120
        f16x8 v = *(const f16x8*)(Wh + (size_t)r * DF + c8);
        *(f16x8*)(Wl + r * WPITCHH + c8) = v;
    }
    __syncthreads();
    if (m0 >= N) return;

    f32x4 acc[8];
    #pragma unroll
    for (int nt = 0; nt < 8; ++nt) acc[nt] = (f32x4){0.f, 0.f, 0.f, 0.f};

    const int xrow = min(m0 + l15, N - 1);         // clamp (dup read) for tail
    #pragma unroll
    for (int kc = 0; kc < DF; kc += 32) {
        const float* xp = X + (size_t)xrow * DF + kc + q * 8;
        float4 xa = *(const float4*)xp;
        float4 xb = *(const float4*)(xp + 4);
        f16x8 A;
        A[0] = (_Float16)xa.x; A[1] = (_Float16)xa.y;
        A[2] = (_Float16)xa.z; A[3] = (_Float16)xa.w;
        A[4] = (_Float16)xb.x; A[5] = (_Float16)xb.y;
        A[6] = (_Float16)xb.z; A[7] = (_Float16)xb.w;
        #pragma unroll
        for (int nt = 0; nt < 8; ++nt) {
            f16x8 B = *(const f16x8*)(Wl + (nt * 16 + l15) * WPITCHH + kc + q * 8);
            // swapped: first operand = W rows (o), second = X rows (node)
            acc[nt] = __builtin_amdgcn_mfma_f32_16x16x32_f16(B, A, acc[nt], 0, 0, 0);
        }
    }

    // ---- epilogue: lane l15 owns node row m0+l15; per nt: 4 consecutive
    //      o-cols (nt*16 + q*4 + r) -> one f16x4 (8 B) store each ----
    const int mrow = m0 + l15;
    if (mrow < N) {
        _Float16* rowp = (_Float16*)S + (size_t)mrow * DF;
        #pragma unroll
        for (int nt = 0; nt < 8; ++nt) {
            float4 bv = *(const float4*)(bias + nt * 16 + q * 4);
            f16x4 hv;
            hv[0] = (_Float16)(acc[nt][0] + bv.x);
            hv[1] = (_Float16)(acc[nt][1] + bv.y);
            hv[2] = (_Float16)(acc[nt][2] + bv.z);
            hv[3] = (_Float16)(acc[nt][3] + bv.w);
            *(f16x4*)(rowp + nt * 16 + q * 4) = hv;
        }
    }
}

// ---------------------------------------------------------------------------
// Kernel 2: CSR row pointers + packed edge metadata {byte_offset, val_bits}
// + one-time W fp32->fp16 conversion. fp16 S rows are 256 B -> col << 8.
// ---------------------------------------------------------------------------
__global__ __launch_bounds__(256)
void build_meta_kernel(const int* __restrict__ arow, const int* __restrict__ acol,
                       const float* __restrict__ aval, const float* __restrict__ W,
                       int* __restrict__ rowptr, int2* __restrict__ pk,
                       _Float16* __restrict__ Wh, int N, int E)
{
    int e = blockIdx.x * 256 + threadIdx.x;
    if (e >= E) return;
    if (e < DF * DF) Wh[e] = (_Float16)W[e];
    pk[e] = make_int2(acol[e] << 8, __float_as_int(aval[e]));
    int r = arow[e];
    int rprev = (e == 0) ? -1 : arow[e - 1];
    for (int n = rprev + 1; n <= r; ++n) rowptr[n] = e;
    if (e == E - 1) {
        for (int n = r + 1; n <= N; ++n) rowptr[n] = E;
    }
}

// ---------------------------------------------------------------------------
// Kernel 3: out[n][:] = tanh( sum_e val[e]*S_fp16[col[e]][:] ) per CSR row.
// ONE 16-LANE GROUP PER NODE (4 nodes/wave, 16 nodes/block): lane f owns
// features 8f..8f+7 (16 B chunk), so 16 lanes cover the whole 256 B row and
// NO cross-lane reduction is needed. 4-edge unroll: 4 pk loads + 4 gathers
// in flight per group (16 gathers/wave). Padded slots read row 0 with val=0.
// Wave count is N/4 (4x fewer than 1-node-per-wave) -> per-wave overhead
// (rowptr chain, tail, store) amortized over 4 nodes.
// ---------------------------------------------------------------------------
__global__ __launch_bounds__(256)
void agg_tanh_kernel(const __half* __restrict__ S, const int* __restrict__ rowptr,
                     const int2* __restrict__ pk, float* __restrict__ out, int Nn)
{
    const int n  = (blockIdx.x * 256 + threadIdx.x) >> 4;   // node = global group
    if (n >= Nn) return;
    const int f  = threadIdx.x & 15;                        // feature chunk
    const int fb = f * 16;                                  // byte offset in row

    const int start = rowptr[n];
    const int end   = rowptr[n + 1];
    const char* Sb  = (const char*)S;

    float acc[8];
    #pragma unroll
    for (int i = 0; i < 8; ++i) acc[i] = 0.f;

    for (int e = start; e < end; e += 4) {
        int2 p0 = pk[e];
        int2 p1 = (e + 1 < end) ? pk[e + 1] : make_int2(0, 0);
        int2 p2 = (e + 2 < end) ? pk[e + 2] : make_int2(0, 0);
        int2 p3 = (e + 3 < end) ? pk[e + 3] : make_int2(0, 0);
        f16x8 h0 = *(const f16x8*)(Sb + (size_t)(unsigned)p0.x + fb);
        f16x8 h1 = *(const f16x8*)(Sb + (size_t)(unsigned)p1.x + fb);
        f16x8 h2 = *(const f16x8*)(Sb + (size_t)(unsigned)p2.x + fb);
        f16x8 h3 = *(const f16x8*)(Sb + (size_t)(unsigned)p3.x + fb);
        const float v0 = __int_as_float(p0.y);
        const float v1 = __int_as_float(p1.y);
        const float v2 = __int_as_float(p2.y);
        const float v3 = __int_as_float(p3.y);
        #pragma unroll
        for (int i = 0; i < 8; ++i) {
            acc[i] += (float)h0[i] * v0 + (float)h1[i] * v1
                    + (float)h2[i] * v2 + (float)h3[i] * v3;
        }
    }

    float4 o0, o1;
    o0.x = tanhf(acc[0]); o0.y = tanhf(acc[1]);
    o0.z = tanhf(acc[2]); o0.w = tanhf(acc[3]);
    o1.x = tanhf(acc[4]); o1.y = tanhf(acc[5]);
    o1.z = tanhf(acc[6]); o1.w = tanhf(acc[7]);
    float* op = out + (size_t)n * DF + f * 8;
    *(float4*)op       = o0;
    *(float4*)(op + 4) = o1;
}

// ---------------------------------------------------------------------------
extern "C" void kernel_launch(void* const* d_in, const int* in_sizes, int n_in,
                              void* d_out, int out_size, void* d_ws, size_t ws_size,
                              hipStream_t stream)
{
    const float* X    = (const float*)d_in[0];   // [N, 128]
    const float* W    = (const float*)d_in[1];   // [128, 128]
    const float* bias = (const float*)d_in[2];   // [128]
    const int*   arow = (const int*)  d_in[3];   // [E] sorted
    const int*   acol = (const int*)  d_in[4];   // [E]
    const float* aval = (const float*)d_in[5];   // [E]
    float* out = (float*)d_out;

    const int N = in_sizes[0] / DF;
    const int E = in_sizes[3];

    // ws layout: S [N*128 fp16] | Wh [128*128 fp16] | rowptr [N+2] | pk [E int2]
    __half*   S      = (__half*)d_ws;
    _Float16* Wh     = (_Float16*)((char*)d_ws + (size_t)N * DF * sizeof(__half));
    int*      rowptr = (int*)((char*)Wh + (size_t)DF * DF * sizeof(_Float16));
    int2*     pk     = (int2*)(rowptr + (N + 2));

    build_meta_kernel<<<(E + 255) / 256, 256, 0, stream>>>(arow, acol, aval, W,
                                                           rowptr, pk, Wh, N, E);

    gemm_mfma_kernel<<<(N + 63) / 64, 256, 0, stream>>>(X, Wh, bias, S, N);

    agg_tanh_kernel<<<(N * 16 + 255) / 256, 256, 0, stream>>>(S, rowptr, pk, out, N);
}